// Round 3
// baseline (122.872 us; speedup 1.0000x reference)
//
#include <hip/hip_runtime.h>
#include <hip/hip_bf16.h>

typedef float f32x4 __attribute__((ext_vector_type(4)));
typedef __bf16 bf16x8 __attribute__((ext_vector_type(8)));

static constexpr int BB = 32;      // batch
static constexpr int DM = 2560;    // d_model
static constexpr int DI = 5120;    // d_inner
static constexpr int NS = 16;      // ssm state N
static constexpr int RK = 160;     // dt_rank
static constexpr int NJ = 192;     // dt_rank + 2N

__device__ __forceinline__ float sigmoidf_(float x) { return 1.f / (1.f + __expf(-x)); }
__device__ __forceinline__ float softplusf_(float x) {
    return (x > 15.f) ? x : log1pf(__expf(x));
}

__device__ __forceinline__ bf16x8 cvt8(float4 a, float4 b) {
    bf16x8 r;
    r[0] = (__bf16)a.x; r[1] = (__bf16)a.y; r[2] = (__bf16)a.z; r[3] = (__bf16)a.w;
    r[4] = (__bf16)b.x; r[5] = (__bf16)b.y; r[6] = (__bf16)b.z; r[7] = (__bf16)b.w;
    return r;
}

// ---------------------------------------------------------------------------
// LDS-free skinny GEMM: C[b][d] += sum_k W[d][k] * X[b][k], b = 0..31.
// Each lane loads its MFMA fragments DIRECTLY from global (8 consecutive
// floats = 2 x float4, 128B-coalesced per 16-lane row group), converts to
// bf16 in regs. No LDS, no barriers; 1-deep register prefetch pipelines the
// HBM latency. Split-K + dual-matrix select via blockIdx; atomicAdd epilogue
// (C pre-zeroed).
// Fragment layout (verified R1/R2): A row = l&15, k-chunk = (l>>4)*8 + 0..7;
// second MFMA uses k-chunk +32. C/D: col(batch) = l&15, row = (l>>4)*4 + j.
// ---------------------------------------------------------------------------
__global__ __launch_bounds__(256) void gemm32(
    const float* __restrict__ W0, float* __restrict__ C0,
    const float* __restrict__ W1, float* __restrict__ C1,
    const float* __restrict__ X,
    int K, int ldc, int nm, int S, int ksteps)
{
    int bid = blockIdx.x;
    int m = bid % nm;
    int rest = bid / nm;
    int s = rest % S;
    int mat = rest / S;
    const float* W = mat ? W1 : W0;
    float* C = mat ? C1 : C0;

    int d0 = m * 32;
    int k0 = s * (K / S);

    int t  = threadIdx.x;
    int l  = t & 63;
    int wv = t >> 6;            // wave 0..3
    int mh = wv & 1;            // d-half of 32x32 tile
    int nh = wv >> 1;           // batch-half
    int r16 = l & 15;
    int kc  = (l >> 4) * 8;     // 0,8,16,24

    const float* wp = W + (size_t)(d0 + mh * 16 + r16) * K + k0 + kc;
    const float* xp = X + (size_t)(nh * 16 + r16) * K + k0 + kc;

    f32x4 acc = {0.f, 0.f, 0.f, 0.f};

    // prefetch tile 0
    float4 wa = *(const float4*)wp;
    float4 wb = *(const float4*)(wp + 4);
    float4 wc = *(const float4*)(wp + 32);
    float4 wd = *(const float4*)(wp + 36);
    float4 xa = *(const float4*)xp;
    float4 xb = *(const float4*)(xp + 4);
    float4 xc = *(const float4*)(xp + 32);
    float4 xd = *(const float4*)(xp + 36);

    for (int it = 0; it < ksteps - 1; ++it) {
        wp += 64; xp += 64;
        // issue next tile's loads (stay in flight across this tile's compute)
        float4 nwa = *(const float4*)wp;
        float4 nwb = *(const float4*)(wp + 4);
        float4 nwc = *(const float4*)(wp + 32);
        float4 nwd = *(const float4*)(wp + 36);
        float4 nxa = *(const float4*)xp;
        float4 nxb = *(const float4*)(xp + 4);
        float4 nxc = *(const float4*)(xp + 32);
        float4 nxd = *(const float4*)(xp + 36);

        acc = __builtin_amdgcn_mfma_f32_16x16x32_bf16(cvt8(wa, wb), cvt8(xa, xb), acc, 0, 0, 0);
        acc = __builtin_amdgcn_mfma_f32_16x16x32_bf16(cvt8(wc, wd), cvt8(xc, xd), acc, 0, 0, 0);

        wa = nwa; wb = nwb; wc = nwc; wd = nwd;
        xa = nxa; xb = nxb; xc = nxc; xd = nxd;
    }
    acc = __builtin_amdgcn_mfma_f32_16x16x32_bf16(cvt8(wa, wb), cvt8(xa, xb), acc, 0, 0, 0);
    acc = __builtin_amdgcn_mfma_f32_16x16x32_bf16(cvt8(wc, wd), cvt8(xc, xd), acc, 0, 0, 0);

    int b = nh * 16 + r16;                      // batch col
    int dbase = d0 + mh * 16 + (l >> 4) * 4;    // d row
    #pragma unroll
    for (int j = 0; j < 4; ++j)
        atomicAdd(&C[(size_t)b * ldc + dbase + j], acc[j]);
}

// ---------------------------------------------------------------------------
// Depthwise causal conv (k=4, shift register) + SiLU.
// ---------------------------------------------------------------------------
__global__ __launch_bounds__(256) void convk(
    const float* __restrict__ xs_bd, const float* __restrict__ conv_states,
    const float* __restrict__ conv_w, const float* __restrict__ conv_b,
    float* __restrict__ conv_bd)
{
    int d = blockIdx.x * 256 + threadIdx.x;
    int b = blockIdx.y;
    size_t o = (size_t)b * DI + d;
    float v = conv_states[(size_t)(1 * BB + b) * DI + d] * conv_w[0 * DI + d]
            + conv_states[(size_t)(2 * BB + b) * DI + d] * conv_w[1 * DI + d]
            + conv_states[(size_t)(3 * BB + b) * DI + d] * conv_w[2 * DI + d]
            + xs_bd[o] * conv_w[3 * DI + d] + conv_b[d];
    conv_bd[o] = v * sigmoidf_(v);
}

// ---------------------------------------------------------------------------
// dt GEMV: dt[b][d] = softplus(x_db[b,0:160] @ W_dt[d,:] + dt_bias[d]).
// Block = 256 thr = 8 d x 32 b.  Grid = DI/8 = 640 blocks.
// ---------------------------------------------------------------------------
__global__ __launch_bounds__(256) void dtk(
    const float* __restrict__ x_db, const float* __restrict__ W_dt,
    const float* __restrict__ dt_bias, float* __restrict__ dt_bd)
{
    __shared__ float Wdt_s[8][164];
    __shared__ float xdb_s[BB][164];

    int t = threadIdx.x;
    int d0 = blockIdx.x * 8;

    for (int f = t; f < 8 * RK; f += 256) {
        Wdt_s[f / RK][f % RK] = W_dt[(size_t)d0 * RK + f];
    }
    for (int f = t; f < BB * RK; f += 256) {
        int b = f / RK, k = f % RK;
        xdb_s[b][k] = x_db[(size_t)b * NJ + k];
    }
    __syncthreads();

    int b  = t & 31;
    int dl = t >> 5;            // 0..7

    float acc = 0.f;
    #pragma unroll 8
    for (int k4 = 0; k4 < RK / 4; ++k4) {
        f32x4 wv = *(const f32x4*)&Wdt_s[dl][k4 * 4];
        f32x4 xv = *(const f32x4*)&xdb_s[b][k4 * 4];
        acc += wv[0] * xv[0] + wv[1] * xv[1] + wv[2] * xv[2] + wv[3] * xv[3];
    }

    int d = d0 + dl;
    dt_bd[(size_t)b * DI + d] = softplusf_(acc + dt_bias[d]);
}

// ---------------------------------------------------------------------------
// SSM recurrence + D skip + SiLU gate.  One thread per (b,d).
// ---------------------------------------------------------------------------
__global__ __launch_bounds__(256) void ssm2(
    const float* __restrict__ x_db, const float* __restrict__ dt_bd,
    const float* __restrict__ A_log, const float* __restrict__ Dv,
    const float* __restrict__ ssm_state, const float* __restrict__ conv_bd,
    const float* __restrict__ res_bd, float* __restrict__ g_bd)
{
    __shared__ float Bc[NS], Cc[NS];

    int t = threadIdx.x;
    int b = blockIdx.x / (DI / 256);
    int dblk = blockIdx.x % (DI / 256);
    int d = dblk * 256 + t;

    if (t < NS) Bc[t] = x_db[(size_t)b * NJ + RK + t];
    else if (t < 2 * NS) Cc[t - NS] = x_db[(size_t)b * NJ + RK + t];
    __syncthreads();

    size_t off = (size_t)b * DI + d;
    float dt = dt_bd[off];
    float cv = conv_bd[off];
    float rv = res_bd[off];
    float Dd = Dv[d];

    const f32x4* ap = (const f32x4*)(A_log + (size_t)d * NS);
    const f32x4* sp = (const f32x4*)(ssm_state + off * NS);

    float y = 0.f;
    #pragma unroll
    for (int q = 0; q < 4; ++q) {
        f32x4 al = ap[q];
        f32x4 sv = sp[q];
        #pragma unroll
        for (int j = 0; j < 4; ++j) {
            int n = q * 4 + j;
            float dA = __expf(-dt * __expf(al[j]));   // exp(dt * (-exp(A_log)))
            y += (sv[j] * dA + dt * Bc[n] * cv) * Cc[n];
        }
    }
    y += Dd * cv;
    g_bd[off] = y * (rv * sigmoidf_(rv));
}

// ---------------------------------------------------------------------------

extern "C" void kernel_launch(void* const* d_in, const int* in_sizes, int n_in,
                              void* d_out, int out_size, void* d_ws, size_t ws_size,
                              hipStream_t stream)
{
    const float* x           = (const float*)d_in[0];
    const float* conv_states = (const float*)d_in[1];
    const float* conv_w      = (const float*)d_in[2];
    const float* conv_b      = (const float*)d_in[3];
    const float* W_ssm_in    = (const float*)d_in[4];
    const float* W_mlp       = (const float*)d_in[5];
    const float* W_out       = (const float*)d_in[6];
    const float* W_x_proj    = (const float*)d_in[7];
    const float* W_dt        = (const float*)d_in[8];
    const float* dt_bias     = (const float*)d_in[9];
    const float* A_log       = (const float*)d_in[10];
    const float* Dv          = (const float*)d_in[11];
    const float* ssm_state   = (const float*)d_in[12];

    float* out = (float*)d_out;
    float* ws  = (float*)d_ws;

    const size_t BD = (size_t)BB * DI;         // 163840
    float* res_bd  = ws;
    float* xs_bd   = ws + BD;
    float* conv_bd = ws + 2 * BD;
    float* x_db    = ws + 3 * BD;              // 32*192 = 6144
    float* g_bd    = ws + 3 * BD + BB * NJ;
    float* dt_bd   = ws + 4 * BD + BB * NJ;

    // zero the atomically-accumulated buffers (res, xs, x_db) + d_out
    hipMemsetAsync(ws, 0, (3 * BD + BB * NJ) * sizeof(float), stream);
    hipMemsetAsync(d_out, 0, (size_t)out_size * sizeof(float), stream);

    // K1: res = x @ W_mlp.T ; xs = x @ W_ssm_in.T   (K=2560, split-K 4, dual)
    gemm32<<<dim3(160 * 4 * 2), 256, 0, stream>>>(
        W_mlp, res_bd, W_ssm_in, xs_bd, x, DM, DI, 160, 4, (DM / 4) / 64);

    // K1.5: depthwise conv + silu
    convk<<<dim3(DI / 256, BB), 256, 0, stream>>>(xs_bd, conv_states, conv_w, conv_b, conv_bd);

    // K2: x_db = conv @ W_x_proj.T   (D=192, K=5120, split-K 40)
    gemm32<<<dim3(6 * 40), 256, 0, stream>>>(
        W_x_proj, x_db, W_x_proj, x_db, conv_bd, DI, NJ, 6, 40, (DI / 40) / 64);

    // K3a: dt GEMV + softplus
    dtk<<<dim3(DI / 8), 256, 0, stream>>>(x_db, W_dt, dt_bias, dt_bd);

    // K3b: SSM recurrence + gate
    ssm2<<<dim3(BB * (DI / 256)), 256, 0, stream>>>(
        x_db, dt_bd, A_log, Dv, ssm_state, conv_bd, res_bd, g_bd);

    // K4: out = g @ W_out.T   (D=2560, K=5120, split-K 16)
    gemm32<<<dim3(80 * 16), 256, 0, stream>>>(
        W_out, out, W_out, out, g_bd, DI, DM, 80, 16, (DI / 16) / 64);
}